// Round 5
// baseline (960.614 us; speedup 1.0000x reference)
//
#include <hip/hip_runtime.h>
#include <hip/hip_bf16.h>

#define TT 2048
#define BB 8
#define HH 8
#define NNS 32
#define MM (BB * TT)

typedef __attribute__((ext_vector_type(8))) short short8;
typedef __attribute__((ext_vector_type(4))) float f32x4;

__device__ __forceinline__ float bf2f(ushort u) {
    return __uint_as_float(((unsigned)u) << 16);
}
__device__ __forceinline__ ushort f2bf(float f) {
    unsigned x = __float_as_uint(f);
    unsigned r = (x + 0x7fffu + ((x >> 16) & 1u)) >> 16;
    return (ushort)r;
}
__device__ __forceinline__ float sigmoidf_fast(float x) {
    // 1/(1+e^-x) = rcp(1 + exp2(-x*log2e)); saturates correctly at +-inf
    float e = __builtin_amdgcn_exp2f(x * -1.4426950408889634f);
    return __builtin_amdgcn_rcpf(1.0f + e);
}
__device__ __forceinline__ float tanhf_fast(float x) {
    // 1 - 2/(e^{2x}+1); exp2 overflow/underflow saturates to +-1, no clamp needed
    float e = __builtin_amdgcn_exp2f(x * 2.8853900817779268f);
    return fmaf(-2.0f, __builtin_amdgcn_rcpf(e + 1.0f), 1.0f);
}

// x += x_from_lane(ctrl), DPP on the VALU pipe (no LDS)
template<int CTRL>
__device__ __forceinline__ float dpp_add(float x) {
    int y = __builtin_amdgcn_update_dpp(0, __float_as_int(x), CTRL, 0xF, 0xF, true);
    return x + __int_as_float(y);
}
// 16-lane rotate-reduce: every lane of each 16-lane row ends with the row sum.
__device__ __forceinline__ float red16(float x) {
    x = dpp_add<0xB1>(x);    // quad_perm xor1
    x = dpp_add<0x4E>(x);    // quad_perm xor2
    x = dpp_add<0x124>(x);   // row_ror:4
    x = dpp_add<0x128>(x);   // row_ror:8
    return x;
}

// Split 8 fp32 -> bf16 hi + bf16 lo planes, stored as 16B each.
__device__ __forceinline__ void stage8_split(const float* __restrict__ src,
                                             ushort* __restrict__ hi,
                                             ushort* __restrict__ lo) {
    float4 x0 = *reinterpret_cast<const float4*>(src);
    float4 x1 = *reinterpret_cast<const float4*>(src + 4);
    float xs[8] = {x0.x, x0.y, x0.z, x0.w, x1.x, x1.y, x1.z, x1.w};
    ushort h[8], l[8];
#pragma unroll
    for (int i = 0; i < 8; ++i) {
        ushort hh = f2bf(xs[i]);
        h[i] = hh;
        l[i] = f2bf(xs[i] - bf2f(hh));
    }
    *reinterpret_cast<uint4*>(hi) = *reinterpret_cast<const uint4*>(h);
    *reinterpret_cast<uint4*>(lo) = *reinterpret_cast<const uint4*>(l);
}
__device__ __forceinline__ void stage8_hi(const float* __restrict__ src,
                                          ushort* __restrict__ hi) {
    float4 x0 = *reinterpret_cast<const float4*>(src);
    float4 x1 = *reinterpret_cast<const float4*>(src + 4);
    float xs[8] = {x0.x, x0.y, x0.z, x0.w, x1.x, x1.y, x1.z, x1.w};
    ushort h[8];
#pragma unroll
    for (int i = 0; i < 8; ++i) h[i] = f2bf(xs[i]);
    *reinterpret_cast<uint4*>(hi) = *reinterpret_cast<const uint4*>(h);
}

// C[M,N] = act(A[M,K] @ W[N,K]^T), fp32 in/out, split-bf16 MFMA (hi+lo, 3 MFMAs).
template<int ACT>
__global__ __launch_bounds__(256) void gemm_split(
    const float* __restrict__ A,
    const float* __restrict__ W0, const float* __restrict__ W1,
    const float* __restrict__ W2, const float* __restrict__ W3,
    const float* __restrict__ bbeta,
    float* __restrict__ C, int M, int N, int K)
{
    __shared__ __align__(16) ushort Ah[64][40], Al[64][40];
    __shared__ __align__(16) ushort Wh[64][40], Wl[64][40];
    const int n0 = blockIdx.x * 64;
    const int m0 = blockIdx.y * 64;
    const int t  = threadIdx.x;
    const int wave = t >> 6, lane = t & 63;
    const int lr = lane & 15, lq = lane >> 4;

    const float* Wsel;
    {
        int wi = n0 >> 8;
        Wsel = (wi == 0) ? W0 : (wi == 1) ? W1 : (wi == 2) ? W2 : W3;
    }
    const int wr0 = n0 & 255;
    const int ar = t >> 2;
    const int ak = (t & 3) * 8;

    f32x4 acc[4];
#pragma unroll
    for (int c = 0; c < 4; ++c) acc[c] = (f32x4){0.f, 0.f, 0.f, 0.f};

    for (int k0 = 0; k0 < K; k0 += 32) {
        __syncthreads();
        stage8_split(&A[(size_t)(m0 + ar) * K + k0 + ak], &Ah[ar][ak], &Al[ar][ak]);
        stage8_split(&Wsel[(size_t)(wr0 + ar) * K + k0 + ak], &Wh[ar][ak], &Wl[ar][ak]);
        __syncthreads();
        short8 ah = *reinterpret_cast<const short8*>(&Ah[wave * 16 + lr][lq * 8]);
        short8 al = *reinterpret_cast<const short8*>(&Al[wave * 16 + lr][lq * 8]);
#pragma unroll
        for (int c = 0; c < 4; ++c) {
            short8 bh = *reinterpret_cast<const short8*>(&Wh[c * 16 + lr][lq * 8]);
            short8 bl = *reinterpret_cast<const short8*>(&Wl[c * 16 + lr][lq * 8]);
            acc[c] = __builtin_amdgcn_mfma_f32_16x16x32_bf16(ah, bh, acc[c], 0, 0, 0);
            acc[c] = __builtin_amdgcn_mfma_f32_16x16x32_bf16(ah, bl, acc[c], 0, 0, 0);
            acc[c] = __builtin_amdgcn_mfma_f32_16x16x32_bf16(al, bh, acc[c], 0, 0, 0);
        }
    }

#pragma unroll
    for (int c = 0; c < 4; ++c) {
#pragma unroll
        for (int r2 = 0; r2 < 4; ++r2) {
            int mg = m0 + wave * 16 + lq * 4 + r2;
            int ng = n0 + c * 16 + lr;
            float v = acc[c][r2];
            if (ACT == 1) v = v * sigmoidf_fast(v);
            if (ACT == 2 && ng >= 768) v = sigmoidf_fast(v + bbeta[ng - 768]);
            C[(size_t)mg * N + ng] = v;
        }
    }
}

// GEMM3: A is bf16 (cell), W fp32 -> bf16 hi only, C fp32.
__global__ __launch_bounds__(256) void gemm_bf_a(
    const ushort* __restrict__ A,
    const float* __restrict__ W0, const float* __restrict__ W1,
    const float* __restrict__ W2, const float* __restrict__ W3,
    float* __restrict__ C, int M, int N, int K)
{
    __shared__ __align__(16) ushort As[64][40];
    __shared__ __align__(16) ushort Ws[64][40];
    const int n0 = blockIdx.x * 64;
    const int m0 = blockIdx.y * 64;
    const int t  = threadIdx.x;
    const int wave = t >> 6, lane = t & 63;
    const int lr = lane & 15, lq = lane >> 4;

    const float* Wsel;
    {
        int wi = n0 >> 8;
        Wsel = (wi == 0) ? W0 : (wi == 1) ? W1 : (wi == 2) ? W2 : W3;
    }
    const int wr0 = n0 & 255;
    const int ar = t >> 2;
    const int ak = (t & 3) * 8;

    f32x4 acc[4];
#pragma unroll
    for (int c = 0; c < 4; ++c) acc[c] = (f32x4){0.f, 0.f, 0.f, 0.f};

    for (int k0 = 0; k0 < K; k0 += 32) {
        __syncthreads();
        *reinterpret_cast<uint4*>(&As[ar][ak]) =
            *reinterpret_cast<const uint4*>(&A[(size_t)(m0 + ar) * K + k0 + ak]);
        stage8_hi(&Wsel[(size_t)(wr0 + ar) * K + k0 + ak], &Ws[ar][ak]);
        __syncthreads();
        short8 af = *reinterpret_cast<const short8*>(&As[wave * 16 + lr][lq * 8]);
#pragma unroll
        for (int c = 0; c < 4; ++c) {
            short8 bfv = *reinterpret_cast<const short8*>(&Ws[c * 16 + lr][lq * 8]);
            acc[c] = __builtin_amdgcn_mfma_f32_16x16x32_bf16(af, bfv, acc[c], 0, 0, 0);
        }
    }

#pragma unroll
    for (int c = 0; c < 4; ++c) {
#pragma unroll
        for (int r2 = 0; r2 < 4; ++r2) {
            int mg = m0 + wave * 16 + lq * 4 + r2;
            int ng = n0 + c * 16 + lr;
            C[(size_t)mg * N + ng] = acc[c][r2];
        }
    }
}

// Recurrent scan, fp32. One wave per 8 rows of one (b,h): two independent
// 4-row register chains (A/B) interleaved for latency hiding; shared kn chain
// and shared k/q loads. DPP reductions, distance-3 register prefetch,
// XCD-local batch mapping. 256 blocks x 64 threads = 1 wave/CU.
__global__ __launch_bounds__(64) void scan_kernel(
    const float* __restrict__ P,
    ushort* __restrict__ cell,     // [B*T, 256] bf16
    float* __restrict__ Sout)      // [B,H,32,32] fp32
{
    const int b    = blockIdx.x & 7;     // XCD-local batch slice
    const int r    = blockIdx.x >> 3;    // 0..31
    const int h    = r & 7;
    const int quad = r >> 3;             // 0..3
    const int l    = threadIdx.x & 15;
    const int iw   = threadIdx.x >> 4;   // 0..3
    const int iA   = quad * 8 + iw;
    const int iB   = iA + 4;

    const float* pb = P + (size_t)b * TT * 1024;
    const int ok0 = h * 32 + l,        ok1 = ok0 + 16;
    const int oq0 = 512 + h * 32 + l,  oq1 = oq0 + 16;
    const int ovA = 256 + h * 32 + iA, obA = 768 + h * 32 + iA;
    const int ovB = 256 + h * 32 + iB, obB = 768 + h * 32 + iB;

    // rotating prefetch file: row t in slot t&3
    float rk0[4], rk1[4], rq0[4], rq1[4], rvA[4], rbA[4], rvB[4], rbB[4];
#pragma unroll
    for (int d = 0; d < 3; ++d) {
        const float* row = pb + (size_t)d * 1024;
        rk0[d] = row[ok0]; rk1[d] = row[ok1];
        rq0[d] = row[oq0]; rq1[d] = row[oq1];
        rvA[d] = row[ovA]; rbA[d] = row[obA];
        rvB[d] = row[ovB]; rbB[d] = row[obB];
    }
    float ks  = red16(fmaf(rk0[0], rk0[0], rk1[0] * rk1[0]));
    float inv = __builtin_amdgcn_rcpf(__builtin_amdgcn_sqrtf(ks) + 1e-6f);
    float kn0 = rk0[0] * inv, kn1 = rk1[0] * inv;
    float q0 = rq0[0], q1 = rq1[0];
    float vA = rvA[0], bA = rbA[0], vB = rvB[0], bB = rbB[0];

    float S0A = 0.f, S1A = 0.f, S0B = 0.f, S1B = 0.f;
    const size_t cb = (size_t)b * TT * 256 + h * 32;

#pragma unroll 4
    for (int t = 0; t < TT; ++t) {
        // issue loads for row t+3
        {
            int rr = (t + 3 < TT) ? (t + 3) : (TT - 1);
            int d3 = (t + 3) & 3;
            const float* row = pb + (size_t)rr * 1024;
            rk0[d3] = row[ok0]; rk1[d3] = row[ok1];
            rq0[d3] = row[oq0]; rq1[d3] = row[oq1];
            rvA[d3] = row[ovA]; rbA[d3] = row[obA];
            rvB[d3] = row[ovB]; rbB[d3] = row[obB];
        }

        // two independent recurrence chains, interleaved
        float pA = red16(fmaf(S0A, kn0, S1A * kn1));
        float pB = red16(fmaf(S0B, kn0, S1B * kn1));
        float dA = vA - pA;
        float dB = vB - pB;
        S0A = tanhf_fast(fmaf(bA, S0A, dA * kn0));
        S0B = tanhf_fast(fmaf(bB, S0B, dB * kn0));
        S1A = tanhf_fast(fmaf(bA, S1A, dA * kn1));
        S1B = tanhf_fast(fmaf(bB, S1B, dB * kn1));

        // shared kn prep for t+1 (independent of S chains)
        int d1 = (t + 1) & 3;
        float nks  = red16(fmaf(rk0[d1], rk0[d1], rk1[d1] * rk1[d1]));
        float ninv = __builtin_amdgcn_rcpf(__builtin_amdgcn_sqrtf(nks) + 1e-6f);

        // outputs (off the recurrence chain)
        float sqA = red16(fmaf(S0A, q0, S1A * q1));
        float sqB = red16(fmaf(S0B, q0, S1B * q1));
        if (l == 0) {
            float oA = sqA * sqA * sigmoidf_fast(sqA);
            float oB = sqB * sqB * sigmoidf_fast(sqB);
            cell[cb + (size_t)t * 256 + iA] = f2bf(oA);
            cell[cb + (size_t)t * 256 + iB] = f2bf(oB);
        }

        kn0 = rk0[d1] * ninv; kn1 = rk1[d1] * ninv;
        q0 = rq0[d1]; q1 = rq1[d1];
        vA = rvA[d1]; bA = rbA[d1];
        vB = rvB[d1]; bB = rbB[d1];
    }

    float* soA = Sout + (((size_t)(b * HH + h)) * NNS + iA) * NNS;
    soA[l] = S0A; soA[l + 16] = S1A;
    float* soB = Sout + (((size_t)(b * HH + h)) * NNS + iB) * NNS;
    soB[l] = S0B; soB[l + 16] = S1B;
}

extern "C" void kernel_launch(void* const* d_in, const int* in_sizes, int n_in,
                              void* d_out, int out_size, void* d_ws, size_t ws_size,
                              hipStream_t stream) {
    const float* x     = (const float*)d_in[0];
    const float* W_in  = (const float*)d_in[1];
    const float* W_k   = (const float*)d_in[2];
    const float* W_v   = (const float*)d_in[3];
    const float* W_q   = (const float*)d_in[4];
    const float* W_b   = (const float*)d_in[5];
    const float* b_b   = (const float*)d_in[6];
    const float* W_out = (const float*)d_in[7];
    float* out = (float*)d_out;

    const int M = MM;                                    // 16384
    float*  xp   = (float*)d_ws;                         // M*1024 fp32
    float*  P    = xp + (size_t)M * 1024;                // M*1024 fp32
    ushort* cell = (ushort*)(P + (size_t)M * 1024);      // M*256 bf16

    dim3 blk(256);
    dim3 g1(1024 / 64, M / 64);

    // 1) xp = silu(x @ W_in^T)
    gemm_split<1><<<g1, blk, 0, stream>>>(x, W_in, W_in + 256 * 1024,
                                          W_in + 512 * 1024, W_in + 768 * 1024,
                                          b_b, xp, M, 1024, 1024);
    // 2) P = xp @ [Wk;Wv;Wq;Wbeta]^T, beta block: sigmoid(. + b_beta)
    gemm_split<2><<<g1, blk, 0, stream>>>(xp, W_k, W_v, W_q, W_b,
                                          b_b, P, M, 1024, 1024);
    // 3) recurrent scan -> cell (bf16) + S_final (fp32, d_out tail)
    scan_kernel<<<dim3(256), dim3(64), 0, stream>>>(P, cell, out + (size_t)M * 1024);
    // 4) y = cell @ W_out^T
    gemm_bf_a<<<g1, blk, 0, stream>>>(cell, W_out, W_out + 256 * 256,
                                      W_out + 512 * 256, W_out + 768 * 256,
                                      out, M, 1024, 256);
}

// Round 6
// 756.508 us; speedup vs baseline: 1.2698x; 1.2698x over previous
//
#include <hip/hip_runtime.h>
#include <hip/hip_bf16.h>

#define TT 2048
#define BB 8
#define HH 8
#define NNS 32
#define MM (BB * TT)

typedef __attribute__((ext_vector_type(8))) short short8;
typedef __attribute__((ext_vector_type(4))) float f32x4;

__device__ __forceinline__ float bf2f(ushort u) {
    return __uint_as_float(((unsigned)u) << 16);
}
__device__ __forceinline__ ushort f2bf(float f) {
    unsigned x = __float_as_uint(f);
    unsigned r = (x + 0x7fffu + ((x >> 16) & 1u)) >> 16;
    return (ushort)r;
}
__device__ __forceinline__ float sigmoidf_fast(float x) {
    float e = __builtin_amdgcn_exp2f(x * -1.4426950408889634f);
    return __builtin_amdgcn_rcpf(1.0f + e);
}
__device__ __forceinline__ float tanhf_fast(float x) {
    // 1 - 2/(e^{2x}+1); exp2 over/underflow saturates to +-1, no clamp needed
    float e = __builtin_amdgcn_exp2f(x * 2.8853900817779268f);
    return fmaf(-2.0f, __builtin_amdgcn_rcpf(e + 1.0f), 1.0f);
}

template<int CTRL>
__device__ __forceinline__ float dpp_add(float x) {
    int y = __builtin_amdgcn_update_dpp(0, __float_as_int(x), CTRL, 0xF, 0xF, true);
    return x + __int_as_float(y);
}
// 16-lane rotate-reduce: every lane of each 16-lane row ends with the row sum.
__device__ __forceinline__ float red16(float x) {
    x = dpp_add<0xB1>(x);    // quad_perm xor1
    x = dpp_add<0x4E>(x);    // quad_perm xor2
    x = dpp_add<0x124>(x);   // row_ror:4
    x = dpp_add<0x128>(x);   // row_ror:8
    return x;
}

// Split 8 fp32 -> bf16 hi + bf16 lo planes, stored as 16B each.
__device__ __forceinline__ void stage8_split(const float* __restrict__ src,
                                             ushort* __restrict__ hi,
                                             ushort* __restrict__ lo) {
    float4 x0 = *reinterpret_cast<const float4*>(src);
    float4 x1 = *reinterpret_cast<const float4*>(src + 4);
    float xs[8] = {x0.x, x0.y, x0.z, x0.w, x1.x, x1.y, x1.z, x1.w};
    ushort h[8], l[8];
#pragma unroll
    for (int i = 0; i < 8; ++i) {
        ushort hh = f2bf(xs[i]);
        h[i] = hh;
        l[i] = f2bf(xs[i] - bf2f(hh));
    }
    *reinterpret_cast<uint4*>(hi) = *reinterpret_cast<const uint4*>(h);
    *reinterpret_cast<uint4*>(lo) = *reinterpret_cast<const uint4*>(l);
}
__device__ __forceinline__ void stage8_hi(const float* __restrict__ src,
                                          ushort* __restrict__ hi) {
    float4 x0 = *reinterpret_cast<const float4*>(src);
    float4 x1 = *reinterpret_cast<const float4*>(src + 4);
    float xs[8] = {x0.x, x0.y, x0.z, x0.w, x1.x, x1.y, x1.z, x1.w};
    ushort h[8];
#pragma unroll
    for (int i = 0; i < 8; ++i) h[i] = f2bf(xs[i]);
    *reinterpret_cast<uint4*>(hi) = *reinterpret_cast<const uint4*>(h);
}

// C[M,N] = act(A[M,K] @ W[N,K]^T), fp32 in/out, split-bf16 MFMA (hi+lo, 3 MFMAs).
template<int ACT>
__global__ __launch_bounds__(256) void gemm_split(
    const float* __restrict__ A,
    const float* __restrict__ W0, const float* __restrict__ W1,
    const float* __restrict__ W2, const float* __restrict__ W3,
    const float* __restrict__ bbeta,
    float* __restrict__ C, int M, int N, int K)
{
    __shared__ __align__(16) ushort Ah[64][40], Al[64][40];
    __shared__ __align__(16) ushort Wh[64][40], Wl[64][40];
    const int n0 = blockIdx.x * 64;
    const int m0 = blockIdx.y * 64;
    const int t  = threadIdx.x;
    const int wave = t >> 6, lane = t & 63;
    const int lr = lane & 15, lq = lane >> 4;

    const float* Wsel;
    {
        int wi = n0 >> 8;
        Wsel = (wi == 0) ? W0 : (wi == 1) ? W1 : (wi == 2) ? W2 : W3;
    }
    const int wr0 = n0 & 255;
    const int ar = t >> 2;
    const int ak = (t & 3) * 8;

    f32x4 acc[4];
#pragma unroll
    for (int c = 0; c < 4; ++c) acc[c] = (f32x4){0.f, 0.f, 0.f, 0.f};

    for (int k0 = 0; k0 < K; k0 += 32) {
        __syncthreads();
        stage8_split(&A[(size_t)(m0 + ar) * K + k0 + ak], &Ah[ar][ak], &Al[ar][ak]);
        stage8_split(&Wsel[(size_t)(wr0 + ar) * K + k0 + ak], &Wh[ar][ak], &Wl[ar][ak]);
        __syncthreads();
        short8 ah = *reinterpret_cast<const short8*>(&Ah[wave * 16 + lr][lq * 8]);
        short8 al = *reinterpret_cast<const short8*>(&Al[wave * 16 + lr][lq * 8]);
#pragma unroll
        for (int c = 0; c < 4; ++c) {
            short8 bh = *reinterpret_cast<const short8*>(&Wh[c * 16 + lr][lq * 8]);
            short8 bl = *reinterpret_cast<const short8*>(&Wl[c * 16 + lr][lq * 8]);
            acc[c] = __builtin_amdgcn_mfma_f32_16x16x32_bf16(ah, bh, acc[c], 0, 0, 0);
            acc[c] = __builtin_amdgcn_mfma_f32_16x16x32_bf16(ah, bl, acc[c], 0, 0, 0);
            acc[c] = __builtin_amdgcn_mfma_f32_16x16x32_bf16(al, bh, acc[c], 0, 0, 0);
        }
    }

#pragma unroll
    for (int c = 0; c < 4; ++c) {
#pragma unroll
        for (int r2 = 0; r2 < 4; ++r2) {
            int mg = m0 + wave * 16 + lq * 4 + r2;
            int ng = n0 + c * 16 + lr;
            float v = acc[c][r2];
            if (ACT == 1) v = v * sigmoidf_fast(v);
            if (ACT == 2 && ng >= 768) v = sigmoidf_fast(v + bbeta[ng - 768]);
            C[(size_t)mg * N + ng] = v;
        }
    }
}

// GEMM3: A is bf16 (cell), W fp32 -> bf16 hi only, C fp32.
__global__ __launch_bounds__(256) void gemm_bf_a(
    const ushort* __restrict__ A,
    const float* __restrict__ W0, const float* __restrict__ W1,
    const float* __restrict__ W2, const float* __restrict__ W3,
    float* __restrict__ C, int M, int N, int K)
{
    __shared__ __align__(16) ushort As[64][40];
    __shared__ __align__(16) ushort Ws[64][40];
    const int n0 = blockIdx.x * 64;
    const int m0 = blockIdx.y * 64;
    const int t  = threadIdx.x;
    const int wave = t >> 6, lane = t & 63;
    const int lr = lane & 15, lq = lane >> 4;

    const float* Wsel;
    {
        int wi = n0 >> 8;
        Wsel = (wi == 0) ? W0 : (wi == 1) ? W1 : (wi == 2) ? W2 : W3;
    }
    const int wr0 = n0 & 255;
    const int ar = t >> 2;
    const int ak = (t & 3) * 8;

    f32x4 acc[4];
#pragma unroll
    for (int c = 0; c < 4; ++c) acc[c] = (f32x4){0.f, 0.f, 0.f, 0.f};

    for (int k0 = 0; k0 < K; k0 += 32) {
        __syncthreads();
        *reinterpret_cast<uint4*>(&As[ar][ak]) =
            *reinterpret_cast<const uint4*>(&A[(size_t)(m0 + ar) * K + k0 + ak]);
        stage8_hi(&Wsel[(size_t)(wr0 + ar) * K + k0 + ak], &Ws[ar][ak]);
        __syncthreads();
        short8 af = *reinterpret_cast<const short8*>(&As[wave * 16 + lr][lq * 8]);
#pragma unroll
        for (int c = 0; c < 4; ++c) {
            short8 bfv = *reinterpret_cast<const short8*>(&Ws[c * 16 + lr][lq * 8]);
            acc[c] = __builtin_amdgcn_mfma_f32_16x16x32_bf16(af, bfv, acc[c], 0, 0, 0);
        }
    }

#pragma unroll
    for (int c = 0; c < 4; ++c) {
#pragma unroll
        for (int r2 = 0; r2 < 4; ++r2) {
            int mg = m0 + wave * 16 + lq * 4 + r2;
            int ng = n0 + c * 16 + lr;
            C[(size_t)mg * N + ng] = acc[c][r2];
        }
    }
}

// kn precompute: kn[b,t,h,j] = k / (||k||_h + 1e-6). Parallel over all (b,t,h).
__global__ __launch_bounds__(256) void kn_kernel(
    const float* __restrict__ P, float* __restrict__ KN)
{
    int idx = blockIdx.x * 256 + threadIdx.x;    // over MM*256
    int col = idx & 255;                          // h*32 + j
    int bt  = idx >> 8;
    float k = P[(size_t)bt * 1024 + col];
    float ks = k * k;
    ks += __shfl_xor(ks, 1, 32);  ks += __shfl_xor(ks, 2, 32);
    ks += __shfl_xor(ks, 4, 32);  ks += __shfl_xor(ks, 8, 32);
    ks += __shfl_xor(ks, 16, 32);
    KN[idx] = k * __builtin_amdgcn_rcpf(sqrtf(ks) + 1e-6f);
}

// Recurrent scan, fp32. 512 waves (2/CU), 4 rows/wave, 16 lanes/row (2 cols each).
// DPP rotate-reduce, distance-3 register prefetch (launch_bounds(64,1) so the
// allocator keeps the rotating file live instead of sinking loads), kn hoisted,
// stores batched 8 steps via lane-captured outputs. XCD-local batch mapping.
__global__ __launch_bounds__(64, 1) void scan_kernel(
    const float* __restrict__ P,
    const float* __restrict__ KN,
    ushort* __restrict__ cell,     // [B*T, 256] bf16
    float* __restrict__ Sout)      // [B,H,32,32] fp32
{
    const int b    = blockIdx.x & 7;     // XCD-local batch slice
    const int r    = blockIdx.x >> 3;    // 0..63
    const int h    = r & 7;
    const int quad = r >> 3;             // 0..7
    const int l    = threadIdx.x & 15;
    const int iw   = threadIdx.x >> 4;   // 0..3
    const int i    = quad * 4 + iw;

    const float* pb  = P  + (size_t)b * TT * 1024;
    const float* knb = KN + (size_t)b * TT * 256;
    const int okn0 = h * 32 + l,       okn1 = okn0 + 16;   // stride-256 rows
    const int oq0  = 512 + h * 32 + l, oq1  = oq0 + 16;    // stride-1024 rows
    const int ov   = 256 + h * 32 + i;
    const int ob   = 768 + h * 32 + i;

    // rotating prefetch file: row t in slot t&3, filled 3 iterations ahead
    float rkn0[4], rkn1[4], rq0[4], rq1[4], rv[4], rb[4];
#pragma unroll
    for (int d = 0; d < 3; ++d) {
        const float* prow = pb + (size_t)d * 1024;
        const float* krow = knb + (size_t)d * 256;
        rkn0[d] = krow[okn0]; rkn1[d] = krow[okn1];
        rq0[d]  = prow[oq0];  rq1[d]  = prow[oq1];
        rv[d]   = prow[ov];   rb[d]   = prow[ob];
    }

    float S0 = 0.f, S1 = 0.f, osv = 0.f;
    const size_t cb = (size_t)b * TT * 256 + h * 32 + i;

#pragma unroll 8
    for (int t = 0; t < TT; ++t) {
        // prefetch row t+3 into slot (t+3)&3 (last used at step t-1)
        {
            int rr = (t + 3 < TT) ? (t + 3) : (TT - 1);
            int d3 = (t + 3) & 3;
            const float* prow = pb + (size_t)rr * 1024;
            const float* krow = knb + (size_t)rr * 256;
            rkn0[d3] = krow[okn0]; rkn1[d3] = krow[okn1];
            rq0[d3]  = prow[oq0];  rq1[d3]  = prow[oq1];
            rv[d3]   = prow[ov];   rb[d3]   = prow[ob];
        }

        const int dc = t & 3;
        // recurrence (critical chain: fma + 4 DPP + tanh)
        float p = red16(fmaf(S0, rkn0[dc], S1 * rkn1[dc]));
        float delta = rv[dc] - p;
        S0 = tanhf_fast(fmaf(rb[dc], S0, delta * rkn0[dc]));
        S1 = tanhf_fast(fmaf(rb[dc], S1, delta * rkn1[dc]));

        // output (off the recurrence chain); all lanes have sq after red16
        float sq = red16(fmaf(S0, rq0[dc], S1 * rq1[dc]));
        float o = sq * sq * sigmoidf_fast(sq);   // Sq * silu(Sq)
        osv = (l == (t & 7)) ? o : osv;          // lane t&7 captures step t

        if ((t & 7) == 7) {
            // lanes 0..7 of each 16-group store 8 consecutive steps at once
            if (l < 8) {
                cell[cb + (size_t)(t - 7 + l) * 256] = f2bf(osv);
            }
        }
    }

    float* so = Sout + (((size_t)(b * HH + h)) * NNS + i) * NNS;
    so[l] = S0;
    so[l + 16] = S1;
}

extern "C" void kernel_launch(void* const* d_in, const int* in_sizes, int n_in,
                              void* d_out, int out_size, void* d_ws, size_t ws_size,
                              hipStream_t stream) {
    const float* x     = (const float*)d_in[0];
    const float* W_in  = (const float*)d_in[1];
    const float* W_k   = (const float*)d_in[2];
    const float* W_v   = (const float*)d_in[3];
    const float* W_q   = (const float*)d_in[4];
    const float* W_b   = (const float*)d_in[5];
    const float* b_b   = (const float*)d_in[6];
    const float* W_out = (const float*)d_in[7];
    float* out = (float*)d_out;

    const int M = MM;                                    // 16384
    float*  xp   = (float*)d_ws;                         // M*1024 fp32
    float*  P    = xp + (size_t)M * 1024;                // M*1024 fp32
    float*  KN   = P  + (size_t)M * 1024;                // M*256  fp32
    ushort* cell = (ushort*)(KN + (size_t)M * 256);      // M*256  bf16

    dim3 blk(256);
    dim3 g1(1024 / 64, M / 64);

    // 1) xp = silu(x @ W_in^T)
    gemm_split<1><<<g1, blk, 0, stream>>>(x, W_in, W_in + 256 * 1024,
                                          W_in + 512 * 1024, W_in + 768 * 1024,
                                          b_b, xp, M, 1024, 1024);
    // 2) P = xp @ [Wk;Wv;Wq;Wbeta]^T, beta block: sigmoid(. + b_beta)
    gemm_split<2><<<g1, blk, 0, stream>>>(xp, W_k, W_v, W_q, W_b,
                                          b_b, P, M, 1024, 1024);
    // 3) kn = k / (||k|| + 1e-6)  (parallel, memory-bound)
    kn_kernel<<<dim3((M * 256) / 256), blk, 0, stream>>>(P, KN);
    // 4) recurrent scan -> cell (bf16) + S_final (fp32, d_out tail)
    scan_kernel<<<dim3(512), dim3(64), 0, stream>>>(P, KN, cell, out + (size_t)M * 1024);
    // 5) y = cell @ W_out^T
    gemm_bf_a<<<g1, blk, 0, stream>>>(cell, W_out, W_out + 256 * 256,
                                      W_out + 512 * 256, W_out + 768 * 256,
                                      out, M, 1024, 256);
}